// Round 5
// baseline (364.700 us; speedup 1.0000x reference)
//
#include <hip/hip_runtime.h>

#define SEQ   1024
#define BATCH 1024
#define TAG   32
#define START 30      // TAG-2
#define ENDT  31      // TAG-1
#define PFD   8       // prefetch ring depth (steps)

__device__ __forceinline__ float rdlane(float v, int j) {
    return __uint_as_float(__builtin_amdgcn_readlane(__float_as_uint(v), j));
}

// One wave = one batch. Lanes 0..31 and 32..63 hold identical state (tag i = lane&31).
// Invariant: alpha_i = mA + ln(v_i); v renormalized by v[0] (>0 after step 0) each step.
// __launch_bounds__(64,1): we need only 1 wave/SIMD -> give the allocator the full
// VGPR budget. (R4's VGPR_Count=32 => e[32] was SPILLED; that was the hidden stall.)
__global__ __launch_bounds__(64, 1) void crf_fwd_kernel(
    const float* __restrict__ feats,   // (SEQ, BATCH, TAG)
    const float* __restrict__ mask,    // (SEQ, BATCH)
    const float* __restrict__ trans,   // (TAG, TAG)
    float* __restrict__ out)           // (BATCH,)
{
    const int lane = threadIdx.x;
    const int i    = lane & 31;        // tag index (duplicated across wave halves)
    const int b    = blockIdx.x;       // one batch per block/wave

    // ---- len = sum_t mask[t][b]  (mask is monotone 1...1 0...0) ----
    float lsum = 0.0f;
    #pragma unroll
    for (int k = 0; k < SEQ / 64; ++k)
        lsum += mask[(unsigned)((k * 64 + lane) * BATCH + b)];
    #pragma unroll
    for (int k = 32; k >= 1; k >>= 1)
        lsum += __shfl_xor(lsum, k, 64);
    const int len = __builtin_amdgcn_readfirstlane((int)(lsum + 0.5f));

    // ---- E[i][j] = exp(trans[i][j]); NEG entries underflow to exactly 0 ----
    float e[32];
    {
        const float4* tr4 = reinterpret_cast<const float4*>(trans + i * TAG);
        #pragma unroll
        for (int c = 0; c < 8; ++c) {
            float4 t = tr4[c];
            e[4 * c + 0] = __expf(t.x);
            e[4 * c + 1] = __expf(t.y);
            e[4 * c + 2] = __expf(t.z);
            e[4 * c + 3] = __expf(t.w);
        }
    }

    const float* fp = feats + (unsigned)(b * TAG + i);

    // ---- peel t = 0: alpha0 = NEG except START=0  =>  v_i = E[i][START] * e^{f_i} ----
    float v  = e[START] * __expf(fp[0]);
    float mA = 0.0f;

    // ---- prefetch ring for feats (t = 1 .. ) ----
    float fb[PFD];
    #pragma unroll
    for (int p = 0; p < PFD; ++p)
        fb[p] = fp[(unsigned)(1 + p) << 15];

    int t = 1;
    for (; t + PFD <= len; t += PFD) {
        #pragma unroll
        for (int p = 0; p < PFD; ++p) {
            // gather v via readlane (VALU only — no LDS, no memory)
            float r0 = rdlane(v, 0);
            float s0 = r0 * e[0];
            float s1 = 0.f, s2 = 0.f, s3 = 0.f, s4 = 0.f, s5 = 0.f, s6 = 0.f, s7 = 0.f;
            #pragma unroll
            for (int j = 0; j < 4; ++j) {
                if (j) s0 = fmaf(rdlane(v, 8 * j + 0), e[8 * j + 0], s0);
                s1 = fmaf(rdlane(v, 8 * j + 1), e[8 * j + 1], s1);
                s2 = fmaf(rdlane(v, 8 * j + 2), e[8 * j + 2], s2);
                s3 = fmaf(rdlane(v, 8 * j + 3), e[8 * j + 3], s3);
                s4 = fmaf(rdlane(v, 8 * j + 4), e[8 * j + 4], s4);
                s5 = fmaf(rdlane(v, 8 * j + 5), e[8 * j + 5], s5);
                s6 = fmaf(rdlane(v, 8 * j + 6), e[8 * j + 6], s6);
                s7 = fmaf(rdlane(v, 8 * j + 7), e[8 * j + 7], s7);
            }
            float dot = ((s0 + s1) + (s2 + s3)) + ((s4 + s5) + (s6 + s7));

            float ef = __expf(fb[p]);                 // off-chain
            float rr = __builtin_amdgcn_rcpf(r0);     // normalizer (r0 > 0)
            float lg = __logf(r0);                    // off-chain
            v   = dot * ef * rr;
            mA += lg;

            // refill ring for step t+PFD+p (clamped; tail over-read harmless)
            int tn = t + PFD + p; tn = (tn < SEQ) ? tn : (SEQ - 1);
            fb[p] = fp[(unsigned)tn << 15];
        }
    }

    // ---- tail: steps t .. len-1 (ring entry p corresponds to step t+p) ----
    const int rem = len - t;
    for (int p = 0; p < rem; ++p) {
        float r0 = rdlane(v, 0);
        float s0 = r0 * e[0];
        float s1 = 0.f, s2 = 0.f, s3 = 0.f, s4 = 0.f, s5 = 0.f, s6 = 0.f, s7 = 0.f;
        #pragma unroll
        for (int j = 0; j < 4; ++j) {
            if (j) s0 = fmaf(rdlane(v, 8 * j + 0), e[8 * j + 0], s0);
            s1 = fmaf(rdlane(v, 8 * j + 1), e[8 * j + 1], s1);
            s2 = fmaf(rdlane(v, 8 * j + 2), e[8 * j + 2], s2);
            s3 = fmaf(rdlane(v, 8 * j + 3), e[8 * j + 3], s3);
            s4 = fmaf(rdlane(v, 8 * j + 4), e[8 * j + 4], s4);
            s5 = fmaf(rdlane(v, 8 * j + 5), e[8 * j + 5], s5);
            s6 = fmaf(rdlane(v, 8 * j + 6), e[8 * j + 6], s6);
            s7 = fmaf(rdlane(v, 8 * j + 7), e[8 * j + 7], s7);
        }
        float dot = ((s0 + s1) + (s2 + s3)) + ((s4 + s5) + (s6 + s7));
        float ef = __expf(fb[p]);
        float rr = __builtin_amdgcn_rcpf(r0);
        float lg = __logf(r0);
        v   = dot * ef * rr;
        mA += lg;
    }

    // ---- epilogue: out[b] = mA + ln( sum_i v_i * exp(trans[END][i]) ) ----
    float z = v * __expf(trans[ENDT * TAG + i]);
    float mx = z;
    #pragma unroll
    for (int k = 16; k >= 1; k >>= 1)
        mx = fmaxf(mx, __shfl_xor(mx, k, 32));
    float ss = z * __builtin_amdgcn_rcpf(mx);   // mx > 0 (v[0] > 0)
    #pragma unroll
    for (int k = 16; k >= 1; k >>= 1)
        ss += __shfl_xor(ss, k, 32);
    if (lane == 0) out[b] = mA + __logf(mx) + __logf(ss);
}

extern "C" void kernel_launch(void* const* d_in, const int* in_sizes, int n_in,
                              void* d_out, int out_size, void* d_ws, size_t ws_size,
                              hipStream_t stream) {
    const float* feats = (const float*)d_in[0];
    const float* mask  = (const float*)d_in[1];
    const float* trans = (const float*)d_in[2];
    float* out = (float*)d_out;
    crf_fwd_kernel<<<dim3(BATCH), dim3(64), 0, stream>>>(feats, mask, trans, out);
}

// Round 6
// 319.310 us; speedup vs baseline: 1.1422x; 1.1422x over previous
//
#include <hip/hip_runtime.h>

#define SEQ   1024
#define BATCH 1024
#define TAG   32
#define START 30      // TAG-2
#define ENDT  31      // TAG-1
#define PFD   8       // prefetch ring depth (steps)

__device__ __forceinline__ float rdlane(float v, int j) {
    return __uint_as_float(__builtin_amdgcn_readlane(__float_as_uint(v), j));
}

// One CRF step. Phase 1: 32 back-to-back v_readlane (SGPR gather).
// sched_barrier(0) pins the boundary so the readlane->VALU SGPR hazard
// (~5 wait states) is paid ONCE, not 32x (R4/R5's 527 cy/step floor).
__device__ __forceinline__ void crf_step(float& v, float& mA, float fval,
                                         const float* __restrict__ e) {
    float r[32];
    #pragma unroll
    for (int j = 0; j < 32; ++j) r[j] = rdlane(v, j);
    __builtin_amdgcn_sched_barrier(0);

    float s0 = r[0] * e[0];
    float s1 = r[1] * e[1];
    float s2 = r[2] * e[2];
    float s3 = r[3] * e[3];
    float s4 = r[4] * e[4];
    float s5 = r[5] * e[5];
    float s6 = r[6] * e[6];
    float s7 = r[7] * e[7];
    #pragma unroll
    for (int j = 1; j < 4; ++j) {
        s0 = fmaf(r[8 * j + 0], e[8 * j + 0], s0);
        s1 = fmaf(r[8 * j + 1], e[8 * j + 1], s1);
        s2 = fmaf(r[8 * j + 2], e[8 * j + 2], s2);
        s3 = fmaf(r[8 * j + 3], e[8 * j + 3], s3);
        s4 = fmaf(r[8 * j + 4], e[8 * j + 4], s4);
        s5 = fmaf(r[8 * j + 5], e[8 * j + 5], s5);
        s6 = fmaf(r[8 * j + 6], e[8 * j + 6], s6);
        s7 = fmaf(r[8 * j + 7], e[8 * j + 7], s7);
    }
    float dot = ((s0 + s1) + (s2 + s3)) + ((s4 + s5) + (s6 + s7));

    float ef = __expf(fval);                      // off-chain
    float rr = __builtin_amdgcn_rcpf(r[0]);       // r[0] > 0 after peel
    float lg = __logf(r[0]);                      // off-chain (mA only)
    float sc = ef * rr;                           // off-chain combine
    v   = dot * sc;                               // single on-chain mul
    mA += lg;
}

// One wave = one batch; lanes 0..31 == 32..63 (tag i = lane&31).
// Invariant: alpha_i = mA + ln(v_i); v renormalized by v[0] each step.
__global__ __attribute__((amdgpu_waves_per_eu(1, 1)))
__launch_bounds__(64, 1) void crf_fwd_kernel(
    const float* __restrict__ feats,   // (SEQ, BATCH, TAG)
    const float* __restrict__ mask,    // (SEQ, BATCH)
    const float* __restrict__ trans,   // (TAG, TAG)
    float* __restrict__ out)           // (BATCH,)
{
    const int lane = threadIdx.x;
    const int i    = lane & 31;
    const int b    = blockIdx.x;

    // ---- len = sum_t mask[t][b] (monotone 1...1 0...0) ----
    float lsum = 0.0f;
    #pragma unroll
    for (int k = 0; k < SEQ / 64; ++k)
        lsum += mask[(unsigned)((k * 64 + lane) * BATCH + b)];
    #pragma unroll
    for (int k = 32; k >= 1; k >>= 1)
        lsum += __shfl_xor(lsum, k, 64);
    const int len = __builtin_amdgcn_readfirstlane((int)(lsum + 0.5f));

    // ---- E[i][j] = exp(trans[i][j]); NEG entries underflow to exactly 0 ----
    float e[32];
    {
        const float4* tr4 = reinterpret_cast<const float4*>(trans + i * TAG);
        #pragma unroll
        for (int c = 0; c < 8; ++c) {
            float4 t = tr4[c];
            e[4 * c + 0] = __expf(t.x);
            e[4 * c + 1] = __expf(t.y);
            e[4 * c + 2] = __expf(t.z);
            e[4 * c + 3] = __expf(t.w);
        }
    }

    const float* fp = feats + (unsigned)(b * TAG + i);

    // ---- peel t = 0: v_i = E[i][START] * e^{feat_i} ----
    float v  = e[START] * __expf(fp[0]);
    float mA = 0.0f;

    // ---- prefetch ring ----
    float fb[PFD];
    #pragma unroll
    for (int p = 0; p < PFD; ++p)
        fb[p] = fp[(unsigned)(1 + p) << 15];

    int t = 1;
    for (; t + PFD <= len; t += PFD) {
        #pragma unroll
        for (int p = 0; p < PFD; ++p) {
            crf_step(v, mA, fb[p], e);
            int tn = t + PFD + p; tn = (tn < SEQ) ? tn : (SEQ - 1);
            fb[p] = fp[(unsigned)tn << 15];
        }
    }
    const int rem = len - t;
    for (int p = 0; p < rem; ++p)
        crf_step(v, mA, fb[p], e);

    // ---- epilogue: out[b] = mA + ln( sum_i v_i * exp(trans[END][i]) ) ----
    float z = v * __expf(trans[ENDT * TAG + i]);
    float mx = z;
    #pragma unroll
    for (int k = 16; k >= 1; k >>= 1)
        mx = fmaxf(mx, __shfl_xor(mx, k, 32));
    float ss = z * __builtin_amdgcn_rcpf(mx);   // mx > 0 (v[0] > 0)
    #pragma unroll
    for (int k = 16; k >= 1; k >>= 1)
        ss += __shfl_xor(ss, k, 32);
    if (lane == 0) out[b] = mA + __logf(mx) + __logf(ss);
}

extern "C" void kernel_launch(void* const* d_in, const int* in_sizes, int n_in,
                              void* d_out, int out_size, void* d_ws, size_t ws_size,
                              hipStream_t stream) {
    const float* feats = (const float*)d_in[0];
    const float* mask  = (const float*)d_in[1];
    const float* trans = (const float*)d_in[2];
    float* out = (float*)d_out;
    crf_fwd_kernel<<<dim3(BATCH), dim3(64), 0, stream>>>(feats, mask, trans, out);
}